// Round 9
// baseline (286.403 us; speedup 1.0000x reference)
//
#include <hip/hip_runtime.h>
#include <hip/hip_bf16.h>

// Fused: out[m,:] = relu( (softmax_n(relu([pus|pis|pss]@W1+b1)@W2+b2) .
//                          relu([C|pss]@WR+bR)) @ Wo + bo )
// R9: one 1024-thread block per m (16 waves, 4x4 grid, 32x32 out/wave).
// K-step = 128 (a full tensor per step): 5 compute steps, 4 staged tiles —
// pss's bf16 LDS tile (staged for GEMM1 step 2) is REUSED as GEMM2's second
// half (no pss re-read: 840 MB total HBM = byte floor). Double-buffered
// Xs[2][128][128]; X staged f32->bf16 with XOR swizzle; all tensor fetches
// issued in the first half via depth-2 reg prefetch; all waits are register
// dependencies (no global_load_lds, no manual vmcnt). Barriers: 4 stage +
// epilogue only.

#define M_ 4096
#define N_ 100
#define E_ 128

typedef __bf16 bf16x8 __attribute__((ext_vector_type(8)));
typedef float  f32x4  __attribute__((ext_vector_type(4)));

// W1p[ck][n][j] = bf16(W1[ck*8+j][n]), ck<48 (K=384)
// WRp[ck][n][j] = bf16(WR[ck*8+j][n]), ck<32 (K=256)
__global__ void prep_weights(const float* __restrict__ W1, const float* __restrict__ WR,
                             __bf16* __restrict__ W1p, __bf16* __restrict__ WRp) {
    int i = blockIdx.x * 256 + threadIdx.x;          // 320*256 == 49152+32768
    if (i < 48 * 128 * 8) {
        int ck = i >> 10, n = (i >> 3) & 127, j = i & 7;
        W1p[i] = (__bf16)W1[(ck * 8 + j) * 128 + n];
    } else {
        int t = i - 48 * 128 * 8;
        if (t < 32 * 128 * 8) {
            int ck = t >> 10, n = (t >> 3) & 127, j = t & 7;
            WRp[t] = (__bf16)WR[(ck * 8 + j) * 128 + n];
        }
    }
}

#define LGKMB()                                                   \
    asm volatile("s_waitcnt lgkmcnt(0)" ::: "memory");            \
    __builtin_amdgcn_s_barrier();                                 \
    asm volatile("" ::: "memory")

__global__ __launch_bounds__(1024, 4) void fused(
    const float* __restrict__ pus, const float* __restrict__ pis,
    const float* __restrict__ pss, const float* __restrict__ Cc,
    const __bf16* __restrict__ W1p, const float* __restrict__ b1,
    const float* __restrict__ W2, const float* __restrict__ b2,
    const __bf16* __restrict__ WRp, const float* __restrict__ bR,
    const float* __restrict__ Wo, const float* __restrict__ bo,
    float* __restrict__ out)
{
    __shared__ __align__(16) __bf16 Xs[2][128][128];   // 64 KB, dbuf
    __shared__ float part[4][128];
    __shared__ float sLDS[128];
    __shared__ float wLDS[128];
    __shared__ float pairLDS[128];
    __shared__ float loutp[8][128];

    const int tid  = threadIdx.x;
    const int lane = tid & 63;
    const int wid  = tid >> 6;               // 0..15
    const int wr = wid >> 2, wc = wid & 3;   // 4 x 4 wave grid
    const int g    = lane >> 4;              // k-subgroup 0..3
    const int l15  = lane & 15;
    const int m    = blockIdx.x;
    const long base = (long)m * (N_ * E_);

    // staging addressing: thread -> (row, 16-k segment)
    const int fr  = tid >> 3;                         // 0..127
    const int frc = (fr < N_) ? fr : (N_ - 1);        // clamp pad rows (masked later)
    const long foff = base + (long)frc * E_ + ((tid & 7) << 4);

    // hoisted per-wave operands
    float w2v[2], b1v[2], bRv[2];
    #pragma unroll
    for (int b = 0; b < 2; ++b) {
        int col = wc * 32 + b * 16 + l15;
        w2v[b] = W2[col]; b1v[b] = b1[col]; bRv[b] = bR[col];
    }
    const float b2v = b2[0];

    float4 xvE[4], xvO[4];

    auto fetchT = [&](float4 (&xv)[4], const float* __restrict__ src) {
        const float* p = src + foff;
        xv[0] = *reinterpret_cast<const float4*>(p);
        xv[1] = *reinterpret_cast<const float4*>(p + 4);
        xv[2] = *reinterpret_cast<const float4*>(p + 8);
        xv[3] = *reinterpret_cast<const float4*>(p + 12);
    };
    auto writeT = [&](float4 (&xv)[4], int buf) {
        const int r = fr;
        const int j = tid & 7;                 // 16-bf16 segment -> blocks 2j, 2j+1
        union { __bf16 h[8]; uint4 u; } w0, w1;
        w0.h[0]=(__bf16)xv[0].x; w0.h[1]=(__bf16)xv[0].y;
        w0.h[2]=(__bf16)xv[0].z; w0.h[3]=(__bf16)xv[0].w;
        w0.h[4]=(__bf16)xv[1].x; w0.h[5]=(__bf16)xv[1].y;
        w0.h[6]=(__bf16)xv[1].z; w0.h[7]=(__bf16)xv[1].w;
        w1.h[0]=(__bf16)xv[2].x; w1.h[1]=(__bf16)xv[2].y;
        w1.h[2]=(__bf16)xv[2].z; w1.h[3]=(__bf16)xv[2].w;
        w1.h[4]=(__bf16)xv[3].x; w1.h[5]=(__bf16)xv[3].y;
        w1.h[6]=(__bf16)xv[3].z; w1.h[7]=(__bf16)xv[3].w;
        *reinterpret_cast<uint4*>(&Xs[buf][r][(((2*j)   ^ (r & 15)) << 3)]) = w0.u;
        *reinterpret_cast<uint4*>(&Xs[buf][r][(((2*j+1) ^ (r & 15)) << 3)]) = w1.u;
    };

    f32x4 acc[2][2];
    #pragma unroll
    for (int h = 0; h < 2; ++h)
        #pragma unroll
        for (int cf = 0; cf < 2; ++cf)
            acc[h][cf] = (f32x4){0.f, 0.f, 0.f, 0.f};

    // one K=128 compute step on LDS buffer `buf` with weight chunk base `ckb`
    auto computeG = [&](int buf, const __bf16* __restrict__ Wp, int ckb) {
        #pragma unroll
        for (int kb = 0; kb < 4; ++kb) {
            bf16x8 bfr[2], af[2];
            #pragma unroll
            for (int cf = 0; cf < 2; ++cf) {
                int nn = wc * 32 + cf * 16 + l15;
                bfr[cf] = *reinterpret_cast<const bf16x8*>(
                    Wp + ((long)(ckb + kb * 4 + g) << 10) + nn * 8);
            }
            #pragma unroll
            for (int h = 0; h < 2; ++h) {
                int rr = wr * 32 + h * 16 + l15;
                af[h] = *reinterpret_cast<const bf16x8*>(
                    &Xs[buf][rr][(((kb * 4 + g) ^ (rr & 15)) << 3)]);
            }
            #pragma unroll
            for (int h = 0; h < 2; ++h)
                #pragma unroll
                for (int cf = 0; cf < 2; ++cf)
                    acc[h][cf] = __builtin_amdgcn_mfma_f32_16x16x32_bf16(
                        af[h], bfr[cf], acc[h][cf], 0, 0, 0);
        }
    };

    // ---------------- schedule ----------------
    fetchT(xvE, pus);
    fetchT(xvO, pis);
    writeT(xvE, 0);                 // waits pus regs only (pis stays in flight)
    fetchT(xvE, pss);
    LGKMB();
    computeG(0, W1p, 0);            // s0: pus
    writeT(xvO, 1);
    fetchT(xvO, Cc);
    LGKMB();
    computeG(1, W1p, 16);           // s1: pis
    writeT(xvE, 0);                 // pss (buf0 readers finished at s0)
    LGKMB();
    computeG(0, W1p, 32);           // s2: pss
    writeT(xvO, 1);                 // C (buf1 readers finished at s1); drains with
                                    // epilogue A's first lgkm+barrier

    // ---- epilogue A: scores + softmax ----
    {
        #pragma unroll
        for (int h = 0; h < 2; ++h) {
            #pragma unroll
            for (int r = 0; r < 4; ++r) {
                float ps = 0.f;
                #pragma unroll
                for (int cf = 0; cf < 2; ++cf)
                    ps += fmaxf(acc[h][cf][r] + b1v[cf], 0.f) * w2v[cf];
                ps += __shfl_xor(ps, 1);
                ps += __shfl_xor(ps, 2);
                ps += __shfl_xor(ps, 4);
                ps += __shfl_xor(ps, 8);
                if (l15 == 0)
                    part[wc][wr * 32 + h * 16 + g * 4 + r] = ps;
            }
        }
        LGKMB();
        if (tid < 128)
            sLDS[tid] = part[0][tid] + part[1][tid] + part[2][tid]
                      + part[3][tid] + b2v;
        LGKMB();
        if (wid == 0) {
            float s0 = (lane < N_) ? sLDS[lane] : -3e38f;
            float s1 = (lane + 64 < N_) ? sLDS[lane + 64] : -3e38f;
            float mx = fmaxf(s0, s1);
            #pragma unroll
            for (int off = 1; off < 64; off <<= 1) mx = fmaxf(mx, __shfl_xor(mx, off));
            float e0 = (lane < N_) ? __expf(s0 - mx) : 0.f;
            float e1 = (lane + 64 < N_) ? __expf(s1 - mx) : 0.f;
            float sum = e0 + e1;
            #pragma unroll
            for (int off = 1; off < 64; off <<= 1) sum += __shfl_xor(sum, off);
            float inv = 1.f / sum;
            wLDS[lane]      = e0 * inv;
            wLDS[lane + 64] = e1 * inv;    // pad rows get weight 0
        }
        #pragma unroll
        for (int h = 0; h < 2; ++h)
            #pragma unroll
            for (int cf = 0; cf < 2; ++cf)
                #pragma unroll
                for (int q = 0; q < 4; ++q)
                    acc[h][cf][q] = 0.f;
        LGKMB();                      // wLDS + buf1(C) staged & visible
    }

    computeG(1, WRp, 0);              // s3: C     (GEMM2 k 0..127)
    computeG(0, WRp, 16);             // s4: pss reused from LDS (k 128..255)

    // ---- epilogue B: weighted pooling + lout ----
    {
        float psum[2] = {0.f, 0.f};
        #pragma unroll
        for (int h = 0; h < 2; ++h) {
            #pragma unroll
            for (int r = 0; r < 4; ++r) {
                float wgt = wLDS[wr * 32 + h * 16 + g * 4 + r];
                #pragma unroll
                for (int cf = 0; cf < 2; ++cf)
                    psum[cf] += wgt * fmaxf(acc[h][cf][r] + bRv[cf], 0.f);
            }
        }
        #pragma unroll
        for (int cf = 0; cf < 2; ++cf) {
            psum[cf] += __shfl_xor(psum[cf], 16);
            psum[cf] += __shfl_xor(psum[cf], 32);
        }
        if (lane < 16) {
            #pragma unroll
            for (int cf = 0; cf < 2; ++cf)
                part[wr][wc * 32 + cf * 16 + lane] = psum[cf];
        }
        LGKMB();
        if (tid < 128)
            pairLDS[tid] = part[0][tid] + part[1][tid] + part[2][tid] + part[3][tid];
        LGKMB();
        // lout split-8: p = tid>>7 handles k in [p*16, p*16+16)
        {
            const int e = tid & 127;
            const int p = tid >> 7;
            float o = 0.f;
            #pragma unroll
            for (int k = 0; k < 16; ++k) {
                int kk = p * 16 + k;
                o += pairLDS[kk] * Wo[kk * 128 + e];
            }
            loutp[p][e] = o;
        }
        LGKMB();
        if (tid < 128) {
            float o = bo[tid];
            #pragma unroll
            for (int p = 0; p < 8; ++p) o += loutp[p][tid];
            out[(long)m * 128 + tid] = fmaxf(o, 0.f);
        }
    }
}

extern "C" void kernel_launch(void* const* d_in, const int* in_sizes, int n_in,
                              void* d_out, int out_size, void* d_ws, size_t ws_size,
                              hipStream_t stream) {
    const float* pus = (const float*)d_in[2];
    const float* pis = (const float*)d_in[3];
    const float* pss = (const float*)d_in[4];
    const float* C   = (const float*)d_in[5];
    const float* W1  = (const float*)d_in[6];
    const float* b1  = (const float*)d_in[7];
    const float* W2  = (const float*)d_in[8];
    const float* b2  = (const float*)d_in[9];
    const float* WR  = (const float*)d_in[10];
    const float* bR  = (const float*)d_in[11];
    const float* Wo  = (const float*)d_in[12];
    const float* bo  = (const float*)d_in[13];
    (void)in_sizes; (void)n_in; (void)ws_size;

    // workspace: W1p bf16[48*128*8] | WRp bf16[32*128*8]
    __bf16* W1p = (__bf16*)d_ws;
    __bf16* WRp = W1p + 48 * 128 * 8;

    prep_weights<<<320, 256, 0, stream>>>(W1, WR, W1p, WRp);
    fused<<<M_, 1024, 0, stream>>>(pus, pis, pss, C, W1p, b1, W2, b2,
                                   WRp, bR, Wo, bo, (float*)d_out);
}